// Round 1
// baseline (34.782 us; speedup 1.0000x reference)
//
#include <hip/hip_runtime.h>
#include <float.h>

// BoundaryMaxPooling: B=16, C2=512 (C=256 start + 256 end), T=126.
// out[b,ch,t] = max_{j in [lo(t,ch), hi(t,ch))} feature[b,ch,j], empty -> -FLT_MAX.
// Intervals derived ONLY from segments[0,:,:] (batch 0), per the reference.

#define BB 16
#define C2 512
#define CH 256
#define TT 126

__global__ __launch_bounds__(128) void bmp_kernel(const float* __restrict__ feat,
                                                  const float* __restrict__ seg,
                                                  float* __restrict__ out) {
    __shared__ float row[TT];
    const int bid = blockIdx.x;          // 0 .. B*C2-1
    const int b   = bid >> 9;            // / 512
    const int ch  = bid & 511;           // % 512
    const int t   = threadIdx.x;
    const size_t base = ((size_t)b * C2 + ch) * TT;

    int lo = 0, hi = 0;
    if (t < TT) {
        row[t] = feat[base + t];
        // segments[0, t, 0..3], clipped to [0, 125]
        const float4 sg = *reinterpret_cast<const float4*>(seg + t * 4);
        const float x0 = fminf(fmaxf(sg.x, 0.f), 125.f);
        const float x1 = fminf(fmaxf(sg.y, 0.f), 125.f);
        const float x2 = fminf(fmaxf(sg.z, 0.f), 125.f);
        const float x3 = fminf(fmaxf(sg.w, 0.f), 125.f);
        if (ch < CH) {                   // start-feature interval (wave-uniform branch)
            lo = (int)floorf(x0);
            hi = (int)ceilf(x1);
            if (lo == hi) hi += 1;
        } else {                         // end-feature interval
            lo = (int)floorf(x2);
            hi = (int)ceilf(x3);
            if (lo == hi) lo -= 1;
        }
        lo = max(lo, 0);
        hi = min(hi, TT);
    }
    __syncthreads();
    if (t < TT) {
        float m = -FLT_MAX;              // == np.finfo(float32).min
        for (int j = lo; j < hi; ++j) m = fmaxf(m, row[j]);
        out[base + t] = m;
    }
}

extern "C" void kernel_launch(void* const* d_in, const int* in_sizes, int n_in,
                              void* d_out, int out_size, void* d_ws, size_t ws_size,
                              hipStream_t stream) {
    const float* feat = (const float*)d_in[0];   // (16, 512, 126) f32
    const float* seg  = (const float*)d_in[1];   // (16, 126, 4) f32 — only [0] used
    float* out        = (float*)d_out;           // (16, 512, 126) f32

    bmp_kernel<<<BB * C2, 128, 0, stream>>>(feat, seg, out);
}

// Round 2
// 10.195 us; speedup vs baseline: 3.4116x; 3.4116x over previous
//
#include <hip/hip_runtime.h>
#include <float.h>

// BoundaryMaxPooling: B=16, C2=512 (C=256 start + 256 end), T=126.
// out[b,ch,t] = max_{j in [lo(t,ch), hi(t,ch))} feature[b,ch,j], empty -> -FLT_MAX.
// Intervals derived ONLY from segments[0,:,:] (batch 0), per the reference.
//
// R2: replace divergent serial scan (wave pays max interval length ~120 iters)
// with an LDS sparse-table RMQ: 7 parallel build levels, O(1) exact query.

#define BB 16
#define C2 512
#define CH 256
#define TT 126
#define LVL 7   // 2^6 = 64; covers len up to 126 (k = floor(log2(len)) <= 6)

__global__ __launch_bounds__(128) void bmp_kernel(const float* __restrict__ feat,
                                                  const float* __restrict__ seg,
                                                  float* __restrict__ out) {
    __shared__ float T[LVL][128];        // level-stride 128 floats: 128%32==0, build is conflict-free
    const int bid = blockIdx.x;          // 0 .. B*C2-1
    const int b   = bid >> 9;            // / 512
    const int ch  = bid & 511;           // % 512
    const int t   = threadIdx.x;
    const size_t base = ((size_t)b * C2 + ch) * TT;

    int lo = 0, hi = 0;
    if (t < TT) {
        T[0][t] = feat[base + t];
        // segments[0, t, 0..3], clipped to [0, 125]
        const float4 sg = *reinterpret_cast<const float4*>(seg + t * 4);
        const float x0 = fminf(fmaxf(sg.x, 0.f), 125.f);
        const float x1 = fminf(fmaxf(sg.y, 0.f), 125.f);
        const float x2 = fminf(fmaxf(sg.z, 0.f), 125.f);
        const float x3 = fminf(fmaxf(sg.w, 0.f), 125.f);
        if (ch < CH) {                   // start-feature interval (wave-uniform branch)
            lo = (int)floorf(x0);
            hi = (int)ceilf(x1);
            if (lo == hi) hi += 1;
        } else {                         // end-feature interval
            lo = (int)floorf(x2);
            hi = (int)ceilf(x3);
            if (lo == hi) lo -= 1;
        }
        lo = max(lo, 0);
        hi = min(hi, TT);
    }
    __syncthreads();

    // Build sparse table: T[k][j] = max(feat[j .. min(j+2^k, TT)))
    #pragma unroll
    for (int k = 1; k < LVL; ++k) {
        const int h = 1 << (k - 1);
        float v = 0.f;
        if (t < TT) {
            v = T[k - 1][t];
            if (t + h < TT) v = fmaxf(v, T[k - 1][t + h]);
        }
        // distinct arrays T[k] vs T[k-1]: no read/write hazard within a level
        if (t < TT) T[k][t] = v;
        __syncthreads();
    }

    if (t < TT) {
        const int len = hi - lo;
        float m = -FLT_MAX;              // == np.finfo(float32).min (empty interval)
        if (len > 0) {
            const int k = 31 - __clz(len);       // floor(log2(len)), len in [1,126]
            m = fmaxf(T[k][lo], T[k][hi - (1 << k)]);  // exact: 2^k <= len < 2^(k+1)
        }
        out[base + t] = m;
    }
}

extern "C" void kernel_launch(void* const* d_in, const int* in_sizes, int n_in,
                              void* d_out, int out_size, void* d_ws, size_t ws_size,
                              hipStream_t stream) {
    const float* feat = (const float*)d_in[0];   // (16, 512, 126) f32
    const float* seg  = (const float*)d_in[1];   // (16, 126, 4) f32 — only [0] used
    float* out        = (float*)d_out;           // (16, 512, 126) f32

    bmp_kernel<<<BB * C2, 128, 0, stream>>>(feat, seg, out);
}

// Round 3
// 9.910 us; speedup vs baseline: 3.5098x; 1.0288x over previous
//
#include <hip/hip_runtime.h>
#include <float.h>

// BoundaryMaxPooling: B=16, C2=512 (C=256 start + 256 end), T=126.
// out[b,ch,t] = max_{j in [lo(t,ch), hi(t,ch))} feature[b,ch,j], empty -> -FLT_MAX.
// Intervals derived ONLY from segments[0,:,:] (batch 0), per the reference.
//
// R3: amortize the 7-barrier sparse-table build across 8 rows per block
// (1024 blocks x 256 threads, all co-resident: 4 blocks/CU), padded level
// arrays (no guards in build), bounds precomputed once per block in LDS.

#define TT   126
#define PAD  128
#define ROWS 8
#define LVL  7     // levels k=0..6; k = floor(log2(len)) <= 6 for len <= 126

__global__ __launch_bounds__(256) void bmp_kernel(const float* __restrict__ feat,
                                                  const float* __restrict__ seg,
                                                  float* __restrict__ out) {
    __shared__ float T[LVL][ROWS][PAD];   // 28,672 B
    __shared__ int2  bnd[TT];             // interval per t (block-uniform half)
    const int bid = blockIdx.x;           // 0..1023
    const int tid = threadIdx.x;
    const size_t base = (size_t)bid * (ROWS * TT);  // flat offset of this block's row 0
    const int ch0 = (bid * ROWS) & 511;   // first channel; all 8 rows in same half
    const bool start_half = (ch0 < 256);

    // ---- load 8 rows (coalesced) + pad, compute bounds once ----
    #pragma unroll
    for (int i = 0; i < 4; ++i) {
        const int s = tid + i * 256;      // 0..1023
        const int r = s >> 7, t = s & 127;
        float v = -FLT_MAX;               // pad slots t=126,127 stay -inf
        if (t < TT) v = feat[base + r * TT + t];
        T[0][r][t] = v;
    }
    if (tid < TT) {
        const float4 sg = *reinterpret_cast<const float4*>(seg + tid * 4);
        int lo, hi;
        if (start_half) {
            const float x0 = fminf(fmaxf(sg.x, 0.f), 125.f);
            const float x1 = fminf(fmaxf(sg.y, 0.f), 125.f);
            lo = (int)floorf(x0);
            hi = (int)ceilf(x1);
            if (lo == hi) hi += 1;
        } else {
            const float x2 = fminf(fmaxf(sg.z, 0.f), 125.f);
            const float x3 = fminf(fmaxf(sg.w, 0.f), 125.f);
            lo = (int)floorf(x2);
            hi = (int)ceilf(x3);
            if (lo == hi) lo -= 1;
        }
        lo = max(lo, 0);
        hi = min(hi, TT);
        bnd[tid] = make_int2(lo, hi);
    }
    __syncthreads();

    // ---- build sparse table: T[k][r][t] = max feat[t .. min(t+2^k, TT)) ----
    #pragma unroll
    for (int k = 1; k < LVL; ++k) {
        const int h = 1 << (k - 1);
        float v[4];
        #pragma unroll
        for (int i = 0; i < 4; ++i) {
            const int s = tid + i * 256;
            const int r = s >> 7, t = s & 127;
            const int t2 = min(t + h, 127);        // clamp into -inf pad: exact
            v[i] = fmaxf(T[k - 1][r][t], T[k - 1][r][t2]);
        }
        #pragma unroll
        for (int i = 0; i < 4; ++i) {
            const int s = tid + i * 256;
            T[k][s >> 7][s & 127] = v[i];
        }
        __syncthreads();
    }

    // ---- O(1) exact query per output, coalesced store ----
    #pragma unroll
    for (int i = 0; i < 4; ++i) {
        const int s = tid + i * 256;
        const int r = s >> 7, t = s & 127;
        if (t < TT) {
            const int2 lh = bnd[t];
            const int len = lh.y - lh.x;
            float m = -FLT_MAX;                    // empty interval -> finfo(f32).min
            if (len > 0) {
                const int k = 31 - __clz(len);     // floor(log2(len)), len in [1,126]
                m = fmaxf(T[k][r][lh.x], T[k][r][lh.y - (1 << k)]);
            }
            out[base + r * TT + t] = m;
        }
    }
}

extern "C" void kernel_launch(void* const* d_in, const int* in_sizes, int n_in,
                              void* d_out, int out_size, void* d_ws, size_t ws_size,
                              hipStream_t stream) {
    const float* feat = (const float*)d_in[0];   // (16, 512, 126) f32
    const float* seg  = (const float*)d_in[1];   // (16, 126, 4) f32 — only [0] used
    float* out        = (float*)d_out;           // (16, 512, 126) f32

    bmp_kernel<<<(16 * 512) / ROWS, 256, 0, stream>>>(feat, seg, out);
}

// Round 4
// 9.749 us; speedup vs baseline: 3.5676x; 1.0165x over previous
//
#include <hip/hip_runtime.h>
#include <float.h>

// BoundaryMaxPooling: B=16, C2=512 (C=256 start + 256 end), T=126.
// out[b,ch,t] = max_{j in [lo(t,ch), hi(t,ch))} feature[b,ch,j], empty -> -FLT_MAX.
// Intervals derived ONLY from segments[0,:,:] (batch 0), per the reference.
//
// R4: barrier-free variant. Each wave exclusively owns 2 rows of the LDS
// sparse table -> no __syncthreads (wave64 lockstep + compiler lgkmcnt order
// LDS deps within a wave; wave_barrier is a free compiler fence). Bounds are
// computed in registers (each lane only queries 2 distinct t values).

#define TT   126
#define PAD  128
#define ROWS 8
#define LVL  7     // k = floor(log2(len)) <= 6 for len <= 126

__global__ __launch_bounds__(256) void bmp_kernel(const float* __restrict__ feat,
                                                  const float* __restrict__ seg,
                                                  float* __restrict__ out) {
    __shared__ float T[LVL][ROWS][PAD];   // 28,672 B; wave w owns rows 2w, 2w+1
    const int tid = threadIdx.x;
    const int wv  = tid >> 6;             // wave 0..3
    const int ln  = tid & 63;
    const int bid = blockIdx.x;           // 0..1023
    const bool start_half = ((bid * ROWS) & 511) < 256;   // block-uniform branch

    // ---- interval bounds for this lane's two t values (registers only) ----
    int lo[2], hi[2];
    #pragma unroll
    for (int q = 0; q < 2; ++q) {
        const int t = (q << 6) + ln;                      // 0..127
        const float4 sg = *reinterpret_cast<const float4*>(seg + min(t, TT - 1) * 4);
        int l, h;
        if (start_half) {
            const float x0 = fminf(fmaxf(sg.x, 0.f), 125.f);
            const float x1 = fminf(fmaxf(sg.y, 0.f), 125.f);
            l = (int)floorf(x0);
            h = (int)ceilf(x1);
            if (l == h) h += 1;
        } else {
            const float x2 = fminf(fmaxf(sg.z, 0.f), 125.f);
            const float x3 = fminf(fmaxf(sg.w, 0.f), 125.f);
            l = (int)floorf(x2);
            h = (int)ceilf(x3);
            if (l == h) l -= 1;
        }
        lo[q] = max(l, 0);
        hi[q] = min(h, TT);
    }

    // ---- load this wave's 2 rows into level 0 (coalesced; -inf pad) ----
    #pragma unroll
    for (int i = 0; i < 4; ++i) {
        const int s = (i << 6) + ln;                      // 0..255
        const int r = s >> 7, t = s & 127;
        const int lr = (wv << 1) + r;
        float v = -FLT_MAX;                               // pad t=126,127 stays -inf
        if (t < TT) v = feat[((size_t)bid * ROWS + lr) * TT + t];
        T[0][lr][t] = v;
    }
    __builtin_amdgcn_wave_barrier();

    // ---- build levels 1..6 over wave-private rows: NO __syncthreads ----
    #pragma unroll
    for (int k = 1; k < LVL; ++k) {
        const int h = 1 << (k - 1);
        float v[4];
        #pragma unroll
        for (int i = 0; i < 4; ++i) {
            const int s = (i << 6) + ln;
            const int r = s >> 7, t = s & 127;
            const int lr = (wv << 1) + r;
            v[i] = fmaxf(T[k - 1][lr][t], T[k - 1][lr][min(t + h, 127)]);  // -inf pad: exact
        }
        __builtin_amdgcn_wave_barrier();
        #pragma unroll
        for (int i = 0; i < 4; ++i) {
            const int s = (i << 6) + ln;
            T[k][(wv << 1) + (s >> 7)][s & 127] = v[i];
        }
        __builtin_amdgcn_wave_barrier();
    }

    // ---- O(1) exact query + coalesced store ----
    #pragma unroll
    for (int i = 0; i < 4; ++i) {
        const int s = (i << 6) + ln;
        const int r = s >> 7, t = s & 127;
        const int q = i & 1;                 // t == (q<<6)+ln for this mapping
        if (t < TT) {
            const int lr  = (wv << 1) + r;
            const int len = hi[q] - lo[q];
            float m = -FLT_MAX;              // empty interval -> finfo(f32).min
            if (len > 0) {
                const int k = 31 - __clz(len);                 // floor(log2(len))
                m = fmaxf(T[k][lr][lo[q]], T[k][lr][hi[q] - (1 << k)]);
            }
            out[((size_t)bid * ROWS + lr) * TT + t] = m;
        }
    }
}

extern "C" void kernel_launch(void* const* d_in, const int* in_sizes, int n_in,
                              void* d_out, int out_size, void* d_ws, size_t ws_size,
                              hipStream_t stream) {
    const float* feat = (const float*)d_in[0];   // (16, 512, 126) f32
    const float* seg  = (const float*)d_in[1];   // (16, 126, 4) f32 — only [0] used
    float* out        = (float*)d_out;           // (16, 512, 126) f32

    bmp_kernel<<<(16 * 512) / ROWS, 256, 0, stream>>>(feat, seg, out);
}